// Round 1
// baseline (1039.831 us; speedup 1.0000x reference)
//
#include <hip/hip_runtime.h>
#include <hip/hip_bf16.h>

typedef __attribute__((ext_vector_type(8))) short bf16x8;
typedef __attribute__((ext_vector_type(4))) float f32x4;

#define BATCH 32
#define CIN   128
#define HW    64
#define OUTC  256
#define KH    3

#define BM 128
#define BN 128
#define BK 32
#define PAD 8   // bf16 elements; row stride 80B = 16B-aligned, 2-way-free b128 reads

__global__ __launch_bounds__(256) void conv_igemm_bf16(
    const float* __restrict__ X,   // (32,128,64,64)
    const float* __restrict__ Kw,  // flat (1152, 256) == B matrix
    float* __restrict__ out)       // (32,256,64,64)
{
    __shared__ __hip_bfloat16 As[BM][BK + PAD];  // [m][k]
    __shared__ __hip_bfloat16 Bs[BN][BK + PAD];  // [n][k] (transposed for b128 frag reads)

    const int tid  = threadIdx.x;
    const int wave = tid >> 6;
    const int lane = tid & 63;
    const int lane_mod16 = lane & 15;
    const int lane_div16 = lane >> 4;

    const int mtile = blockIdx.x;        // 0..1023
    const int ntile = blockIdx.y;        // 0..1
    const int m_base = mtile * BM;
    const int b  = m_base >> 12;         // m = b*4096 + y*64 + x
    const int y0 = (m_base & 4095) >> 6; // tile covers rows y0, y0+1
    const int n_base = ntile * BN;

    // 2x2 waves, each owns a 64x64 sub-tile
    const int wm = (wave >> 1) * 64;
    const int wn = (wave & 1) * 64;

    f32x4 acc[4][4] = {}; // [mi][ni]

    // staging thread mapping
    const int smm = tid & 127;       // A row (m) / B row (n)
    const int ccb = tid >> 7;        // 0/1, covers cc with stride 2

    const int sx  = smm & 63;        // x within row
    const int syr = smm >> 6;        // 0/1 (which y row)

    for (int ij = 0; ij < 9; ++ij) {
        const int di = ij / 3 - 1;
        const int dj = ij % 3 - 1;

        const int xp  = sx + dj;
        const int yp  = y0 + syr + di;
        const bool ok = ((unsigned)xp < (unsigned)HW) && ((unsigned)yp < (unsigned)HW);
        // base address for (b, c=0, yp, xp)
        const long xbase = (((long)b * CIN) * HW + yp) * HW + xp;

        for (int c0 = 0; c0 < CIN; c0 += BK) {
            // ---- stage A: As[mm][cc] = X[b, c0+cc, yp, xp] (0 if OOB) ----
            #pragma unroll
            for (int cc = ccb; cc < BK; cc += 2) {
                float v = 0.f;
                if (ok) v = X[xbase + (long)(c0 + cc) * (HW * HW)];
                As[smm][cc] = __float2bfloat16(v);
            }
            // ---- stage B: Bs[nn][cc] = Kw[((c0+cc)*9 + ij)*256 + n_base + nn] ----
            #pragma unroll
            for (int cc = ccb; cc < BK; cc += 2) {
                const int kidx = (c0 + cc) * 9 + ij;
                Bs[smm][cc] = __float2bfloat16(Kw[kidx * OUTC + n_base + smm]);
            }
            __syncthreads();

            // ---- fragments + MFMA ----
            bf16x8 afrag[4], bfrag[4];
            #pragma unroll
            for (int mi = 0; mi < 4; ++mi)
                afrag[mi] = *reinterpret_cast<const bf16x8*>(
                    &As[wm + mi * 16 + lane_mod16][lane_div16 * 8]);
            #pragma unroll
            for (int ni = 0; ni < 4; ++ni)
                bfrag[ni] = *reinterpret_cast<const bf16x8*>(
                    &Bs[wn + ni * 16 + lane_mod16][lane_div16 * 8]);

            #pragma unroll
            for (int mi = 0; mi < 4; ++mi)
                #pragma unroll
                for (int ni = 0; ni < 4; ++ni)
                    acc[mi][ni] = __builtin_amdgcn_mfma_f32_16x16x32_bf16(
                        afrag[mi], bfrag[ni], acc[mi][ni], 0, 0, 0);

            __syncthreads();
        }
    }

    // ---- epilogue: D[row=(lane>>4)*4+r][col=lane&15]; zero y==63 / x==63 ----
    #pragma unroll
    for (int mi = 0; mi < 4; ++mi) {
        #pragma unroll
        for (int ni = 0; ni < 4; ++ni) {
            #pragma unroll
            for (int r = 0; r < 4; ++r) {
                const int mm = wm + mi * 16 + lane_div16 * 4 + r;
                const int nn = wn + ni * 16 + lane_mod16;
                const int y = y0 + (mm >> 6);
                const int x = mm & 63;
                const int o = n_base + nn;
                float v = acc[mi][ni][r];
                if (y == HW - 1 || x == HW - 1) v = 0.f;
                out[(((long)b * OUTC + o) * HW + y) * HW + x] = v;
            }
        }
    }
}

extern "C" void kernel_launch(void* const* d_in, const int* in_sizes, int n_in,
                              void* d_out, int out_size, void* d_ws, size_t ws_size,
                              hipStream_t stream) {
    const float* X  = (const float*)d_in[0];
    const float* Kw = (const float*)d_in[1];
    float* out = (float*)d_out;

    dim3 grid(1024, 2);   // M/128 x N/128
    dim3 block(256);
    conv_igemm_bf16<<<grid, block, 0, stream>>>(X, Kw, out);
}

// Round 3
// 131.747 us; speedup vs baseline: 7.8927x; 7.8927x over previous
//
#include <hip/hip_runtime.h>
#include <hip/hip_bf16.h>

typedef __attribute__((ext_vector_type(8))) short bf16x8;
typedef __attribute__((ext_vector_type(4))) float f32x4;

#define CIN   128
#define HW    64
#define OUTC  256

// ---------------- ws layout ----------------
// Xt : bf16 [32][64][64][128]  (b,y,x,c)  = 33,554,432 B at offset 0
// Bp : bf16 [9][256][128]      (ij,n,c)   =    589,824 B at offset 33,554,432
// zp : 4096 B zero page                     at offset 34,144,256
#define XT_BYTES   33554432ULL
#define BP_OFF     33554432ULL
#define ZP_OFF     34144256ULL
#define WS_NEEDED  34148352ULL

// ================= pass 1: X (b,c,y,x) f32 -> Xt (b,y,x,c) bf16 =================
__global__ __launch_bounds__(256) void conv_prep_x(const float* __restrict__ X,
                                                   __hip_bfloat16* __restrict__ Xt) {
    __shared__ __hip_bfloat16 L[64][136];   // [x][c], pad to 272B rows
    const int b = blockIdx.x >> 6;
    const int y = blockIdx.x & 63;
    const int x = threadIdx.x & 63;
    const int c0 = (threadIdx.x >> 6) * 32;

    const float* src = X + (((long)(b * CIN + c0) * HW + y) * HW + x);
    #pragma unroll
    for (int j = 0; j < 32; j += 2) {
        float v0 = src[(long)j * (HW * HW)];
        float v1 = src[(long)(j + 1) * (HW * HW)];
        __hip_bfloat162 p;
        p.x = __float2bfloat16(v0);
        p.y = __float2bfloat16(v1);
        *reinterpret_cast<__hip_bfloat162*>(&L[x][c0 + j]) = p;
    }
    __syncthreads();

    // 64 x-rows * 128 c = 8192 bf16 = 1024 granules of 8 -> 4 iters * 256 threads
    __hip_bfloat16* dst = Xt + (long)blockIdx.x * (64 * 128);
    #pragma unroll
    for (int it = 0; it < 4; ++it) {
        int G = it * 256 + threadIdx.x;   // granule id: x*16 + g
        int xx = G >> 4, g = G & 15;
        bf16x8 v = *reinterpret_cast<const bf16x8*>(&L[xx][g * 8]);
        *reinterpret_cast<bf16x8*>(&dst[(long)G * 8]) = v;
    }
}

// ================= pass 2: Kw (k=c*9+ij, n) f32 -> Bp (ij,n,c) bf16 =================
__global__ __launch_bounds__(256) void conv_prep_b(const float* __restrict__ Kw,
                                                   __hip_bfloat16* __restrict__ Bp) {
    int idx = blockIdx.x * 256 + threadIdx.x;  // 294912 total
    int c  = idx & 127;
    int n  = (idx >> 7) & 255;
    int ij = idx >> 15;
    Bp[idx] = __float2bfloat16(Kw[((c * 9 + ij) << 8) + n]);
}

// ================= pass 3: implicit-GEMM, m97 structure =================
// M = 131072 (b,y,x), N = 256 (o), K = 9 taps x 128 c
// BM=128 (2 y-rows x 64 x), BN=128, BK=64 (channel chunk), 4 waves 2x2 of 64x64
__global__ __launch_bounds__(256) void conv_igemm2(
    const __hip_bfloat16* __restrict__ Xt,
    const __hip_bfloat16* __restrict__ Bp,
    const __hip_bfloat16* __restrict__ zp,
    float* __restrict__ out) {
    __shared__ __hip_bfloat16 As[128 * 64];  // [m][k] linear, 128B rows, granule-swizzled
    __shared__ __hip_bfloat16 Bs[128 * 64];  // [n][k] linear

    const int tid  = threadIdx.x;
    const int wave = tid >> 6;
    const int lane = tid & 63;
    const int l16  = lane & 15;
    const int d16  = lane >> 4;

    const int mtile = blockIdx.x;            // 0..1023
    const int b  = mtile >> 5;
    const int y0 = (mtile & 31) * 2;
    const int n0 = blockIdx.y * 128;

    const int wm = (wave >> 1) * 64;
    const int wn = (wave & 1) * 64;

    // staging geometry: one global_load_lds = 64 lanes x 16B = 8 rows x 8 granules
    const int lrow = lane >> 3;   // row within 8-row group
    const int lg   = lane & 7;    // LDS granule slot within row

    f32x4 acc[4][4] = {};

    for (int ij = 0; ij < 9; ++ij) {
        const int di = ij / 3 - 1;
        const int dj = ij % 3 - 1;
        const __hip_bfloat16* bpb = Bp + ((long)ij * 256 + n0) * 128;

        for (int c0 = 0; c0 < CIN; c0 += 64) {
            // ---- stage A (im2col rows, OOB -> zero page) ----
            #pragma unroll
            for (int l = 0; l < 4; ++l) {
                const int L = wave * 4 + l;
                const int row = L * 8 + lrow;            // m within tile
                const int srcg = lg ^ (row & 7);         // inverse swizzle on source
                const int x = (row & 63) + dj;
                const int y = y0 + (row >> 6) + di;
                const __hip_bfloat16* gp =
                    ((unsigned)x < (unsigned)HW && (unsigned)y < (unsigned)HW)
                        ? Xt + (((long)b * 4096 + y * 64 + x) * 128 + c0 + srcg * 8)
                        : zp;
                __builtin_amdgcn_global_load_lds(
                    (const __attribute__((address_space(1))) void*)gp,
                    (__attribute__((address_space(3))) void*)(As + L * 512),
                    16, 0, 0);
            }
            // ---- stage B ----
            #pragma unroll
            for (int l = 0; l < 4; ++l) {
                const int L = wave * 4 + l;
                const int row = L * 8 + lrow;            // n within tile
                const int srcg = lg ^ (row & 7);
                const __hip_bfloat16* gp = bpb + ((long)row * 128 + c0 + srcg * 8);
                __builtin_amdgcn_global_load_lds(
                    (const __attribute__((address_space(1))) void*)gp,
                    (__attribute__((address_space(3))) void*)(Bs + L * 512),
                    16, 0, 0);
            }
            __syncthreads();   // compiler drains vmcnt here (m97 structure)

            // ---- fragments (swizzled ds_read_b128) + MFMA ----
            bf16x8 af[2][4], bfr[2][4];
            #pragma unroll
            for (int ks = 0; ks < 2; ++ks) {
                const int g = ks * 4 + d16;
                #pragma unroll
                for (int mi = 0; mi < 4; ++mi) {
                    const int m = wm + mi * 16 + l16;
                    af[ks][mi] = *reinterpret_cast<const bf16x8*>(
                        As + m * 64 + ((g ^ (m & 7)) * 8));
                }
                #pragma unroll
                for (int ni = 0; ni < 4; ++ni) {
                    const int n = wn + ni * 16 + l16;
                    bfr[ks][ni] = *reinterpret_cast<const bf16x8*>(
                        Bs + n * 64 + ((g ^ (n & 7)) * 8));
                }
            }
            #pragma unroll
            for (int ks = 0; ks < 2; ++ks)
                #pragma unroll
                for (int mi = 0; mi < 4; ++mi)
                    #pragma unroll
                    for (int ni = 0; ni < 4; ++ni)
                        acc[mi][ni] = __builtin_amdgcn_mfma_f32_16x16x32_bf16(
                            af[ks][mi], bfr[ks][ni], acc[mi][ni], 0, 0, 0);

            __syncthreads();
        }
    }

    // ---- epilogue: float4 stores; zero y==63 / x==63 ----
    #pragma unroll
    for (int mi = 0; mi < 4; ++mi) {
        const int m = wm + mi * 16 + d16 * 4;   // +r, r=0..3 contiguous in x
        const int x0 = m & 63;
        const int y  = y0 + (m >> 6);
        #pragma unroll
        for (int ni = 0; ni < 4; ++ni) {
            const int o = n0 + wn + ni * 16 + l16;
            float4 v;
            v.x = acc[mi][ni][0];
            v.y = acc[mi][ni][1];
            v.z = acc[mi][ni][2];
            v.w = acc[mi][ni][3];
            if (y == HW - 1) { v.x = v.y = v.z = v.w = 0.f; }
            if (x0 + 3 == HW - 1) v.w = 0.f;
            *reinterpret_cast<float4*>(
                out + ((long)(b * OUTC + o) * 4096 + y * 64 + x0)) = v;
        }
    }
}

// ================= fallback (round-1 kernel) if ws too small =================
__global__ __launch_bounds__(256) void conv_igemm_bf16(
    const float* __restrict__ X, const float* __restrict__ Kw, float* __restrict__ out) {
    __shared__ __hip_bfloat16 As[128][40];
    __shared__ __hip_bfloat16 Bs[128][40];
    const int tid = threadIdx.x, wave = tid >> 6, lane = tid & 63;
    const int l16 = lane & 15, d16 = lane >> 4;
    const int m_base = blockIdx.x * 128;
    const int b = m_base >> 12, y0 = (m_base & 4095) >> 6;
    const int n_base = blockIdx.y * 128;
    const int wm = (wave >> 1) * 64, wn = (wave & 1) * 64;
    f32x4 acc[4][4] = {};
    const int smm = tid & 127, ccb = tid >> 7;
    const int sx = smm & 63, syr = smm >> 6;
    for (int ij = 0; ij < 9; ++ij) {
        const int di = ij / 3 - 1, dj = ij % 3 - 1;
        const int xp = sx + dj, yp = y0 + syr + di;
        const bool ok = ((unsigned)xp < 64u) && ((unsigned)yp < 64u);
        const long xbase = (((long)b * CIN) * HW + yp) * HW + xp;
        for (int c0 = 0; c0 < CIN; c0 += 32) {
            for (int cc = ccb; cc < 32; cc += 2) {
                float v = ok ? X[xbase + (long)(c0 + cc) * 4096] : 0.f;
                As[smm][cc] = __float2bfloat16(v);
                Bs[smm][cc] = __float2bfloat16(Kw[((c0 + cc) * 9 + ij) * OUTC + n_base + smm]);
            }
            __syncthreads();
            bf16x8 afrag[4], bfrag[4];
            for (int mi = 0; mi < 4; ++mi)
                afrag[mi] = *reinterpret_cast<const bf16x8*>(&As[wm + mi * 16 + l16][d16 * 8]);
            for (int ni = 0; ni < 4; ++ni)
                bfrag[ni] = *reinterpret_cast<const bf16x8*>(&Bs[wn + ni * 16 + l16][d16 * 8]);
            for (int mi = 0; mi < 4; ++mi)
                for (int ni = 0; ni < 4; ++ni)
                    acc[mi][ni] = __builtin_amdgcn_mfma_f32_16x16x32_bf16(
                        afrag[mi], bfrag[ni], acc[mi][ni], 0, 0, 0);
            __syncthreads();
        }
    }
    for (int mi = 0; mi < 4; ++mi)
        for (int ni = 0; ni < 4; ++ni)
            for (int r = 0; r < 4; ++r) {
                const int mm = wm + mi * 16 + d16 * 4 + r;
                const int nn = wn + ni * 16 + l16;
                const int y = y0 + (mm >> 6), x = mm & 63, o = n_base + nn;
                float v = acc[mi][ni][r];
                if (y == 63 || x == 63) v = 0.f;
                out[(((long)b * OUTC + o) * HW + y) * HW + x] = v;
            }
}

extern "C" void kernel_launch(void* const* d_in, const int* in_sizes, int n_in,
                              void* d_out, int out_size, void* d_ws, size_t ws_size,
                              hipStream_t stream) {
    const float* X  = (const float*)d_in[0];
    const float* Kw = (const float*)d_in[1];
    float* out = (float*)d_out;

    if (ws_size >= WS_NEEDED) {
        char* ws = (char*)d_ws;
        __hip_bfloat16* Xt = (__hip_bfloat16*)ws;
        __hip_bfloat16* Bp = (__hip_bfloat16*)(ws + BP_OFF);
        __hip_bfloat16* zp = (__hip_bfloat16*)(ws + ZP_OFF);
        hipMemsetAsync(ws + ZP_OFF, 0, 4096, stream);
        conv_prep_x<<<dim3(2048), dim3(256), 0, stream>>>(X, Xt);
        conv_prep_b<<<dim3(1152), dim3(256), 0, stream>>>(Kw, Bp);
        conv_igemm2<<<dim3(1024, 2), dim3(256), 0, stream>>>(Xt, Bp, zp, out);
    } else {
        conv_igemm_bf16<<<dim3(1024, 2), dim3(256), 0, stream>>>(X, Kw, out);
    }
}

// Round 4
// 131.400 us; speedup vs baseline: 7.9135x; 1.0026x over previous
//
#include <hip/hip_runtime.h>
#include <hip/hip_bf16.h>

typedef __attribute__((ext_vector_type(8))) short bf16x8;
typedef __attribute__((ext_vector_type(4))) float f32x4;

#define CIN   128
#define HW    64
#define OUTC  256

// ---------------- ws layout ----------------
// Xt : bf16 [32][64][64][128]  (b,y,x,c)  = 33,554,432 B at offset 0
// Bp : bf16 [9][256][128]      (ij,n,c)   =    589,824 B at offset 33,554,432
// zp : 4096 B zero page                     at offset 34,144,256
#define BP_OFF     33554432ULL
#define ZP_OFF     34144256ULL
#define WS_NEEDED  34148352ULL

// ================= pass 1: X (b,c,y,x) f32 -> Xt (b,y,x,c) bf16 =================
__global__ __launch_bounds__(256) void conv_prep_x(const float* __restrict__ X,
                                                   __hip_bfloat16* __restrict__ Xt) {
    __shared__ __hip_bfloat16 L[64][136];
    const int b = blockIdx.x >> 6;
    const int y = blockIdx.x & 63;
    const int x = threadIdx.x & 63;
    const int c0 = (threadIdx.x >> 6) * 32;

    const float* src = X + (((long)(b * CIN + c0) * HW + y) * HW + x);
    #pragma unroll
    for (int j = 0; j < 32; j += 2) {
        float v0 = src[(long)j * (HW * HW)];
        float v1 = src[(long)(j + 1) * (HW * HW)];
        __hip_bfloat162 p;
        p.x = __float2bfloat16(v0);
        p.y = __float2bfloat16(v1);
        *reinterpret_cast<__hip_bfloat162*>(&L[x][c0 + j]) = p;
    }
    __syncthreads();

    __hip_bfloat16* dst = Xt + (long)blockIdx.x * (64 * 128);
    #pragma unroll
    for (int it = 0; it < 4; ++it) {
        int G = it * 256 + threadIdx.x;
        int xx = G >> 4, g = G & 15;
        bf16x8 v = *reinterpret_cast<const bf16x8*>(&L[xx][g * 8]);
        *reinterpret_cast<bf16x8*>(&dst[(long)G * 8]) = v;
    }
}

// ================= pass 2: Kw (k=c*9+ij, n) f32 -> Bp (ij,n,c) bf16 =================
__global__ __launch_bounds__(256) void conv_prep_b(const float* __restrict__ Kw,
                                                   __hip_bfloat16* __restrict__ Bp) {
    int idx = blockIdx.x * 256 + threadIdx.x;  // 294912 total
    int c  = idx & 127;
    int n  = (idx >> 7) & 255;
    int ij = idx >> 15;
    Bp[idx] = __float2bfloat16(Kw[((c * 9 + ij) << 8) + n]);
}

// ================= pass 3: deep-pipelined implicit GEMM =================
// M=131072, N=256, K=1152 (9 taps x 4 chunks of 32c = 36 K-tiles)
// BM=256 (4 y-rows x 64 x), BN=256, BK=32; 8 waves 2Mx4N, per-wave 128x64
// LDS: 4-deep circular buf x (A 16KB + B 16KB) = 128 KB; stage 3 tiles ahead
// counted s_waitcnt vmcnt(12); raw s_barrier (no implicit vmcnt(0) drain)
#define NT 36
__global__ __launch_bounds__(512, 2) void conv_igemm3(
    const __hip_bfloat16* __restrict__ Xt,
    const __hip_bfloat16* __restrict__ Bp,
    const __hip_bfloat16* __restrict__ zp,
    float* __restrict__ out)
{
    __shared__ __hip_bfloat16 As[4][256 * 32];
    __shared__ __hip_bfloat16 Bs[4][256 * 32];

    const int tid  = threadIdx.x;
    const int wv   = tid >> 6;       // 0..7
    const int lane = tid & 63;
    const int l16  = lane & 15;
    const int d16  = lane >> 4;      // k-granule 0..3
    const int wr   = wv >> 2;        // m-offset 128*wr
    const int wc   = wv & 3;         // n-offset 64*wc

    const int mtile = blockIdx.x;    // 0..511
    const int b  = mtile >> 4;
    const int y0 = (mtile & 15) * 4;

    // staging lane geometry: one load = 16 rows x 4 granules (16B each)
    const int srow = lane >> 2;      // 0..15
    const int sg   = lane & 3;       // LDS granule slot

    f32x4 acc[8][4] = {};

    // swizzle rule (both sides): LDS slot s of row r holds global granule
    // G = (s - (r>>1)) & 3  <=>  granule G lives at slot (G + (r>>1)) & 3.
    auto STAGE = [&](int KT, int BUF) {
        const int ij_ = KT >> 2;
        const int c0_ = (KT & 3) * 32;
        const int di_ = ij_ / 3 - 1;
        const int dj_ = ij_ % 3 - 1;
        #pragma unroll
        for (int l = 0; l < 2; ++l) {                       // A half
            const int r = wv * 32 + l * 16 + srow;
            const int G = (sg - (r >> 1)) & 3;
            const int x_ = (r & 63) + dj_;
            const int y_ = y0 + (r >> 6) + di_;
            const __hip_bfloat16* gp =
                ((unsigned)x_ < 64u && (unsigned)y_ < 64u)
                    ? Xt + (((long)b * 4096 + y_ * 64 + x_) * 128 + c0_ + G * 8)
                    : zp;
            __builtin_amdgcn_global_load_lds(
                (const __attribute__((address_space(1))) void*)gp,
                (__attribute__((address_space(3))) void*)(&As[BUF][(wv * 32 + l * 16) * 32]),
                16, 0, 0);
        }
        #pragma unroll
        for (int l = 0; l < 2; ++l) {                       // B half
            const int r = wv * 32 + l * 16 + srow;
            const int G = (sg - (r >> 1)) & 3;
            const __hip_bfloat16* gp =
                Bp + (((long)ij_ * 256 + r) * 128 + c0_ + G * 8);
            __builtin_amdgcn_global_load_lds(
                (const __attribute__((address_space(1))) void*)gp,
                (__attribute__((address_space(3))) void*)(&Bs[BUF][(wv * 32 + l * 16) * 32]),
                16, 0, 0);
        }
    };

    auto COMPUTE = [&](int BUF) {
        bf16x8 bf_[4], af[8];
        #pragma unroll
        for (int ni = 0; ni < 4; ++ni) {
            const int n = wc * 64 + ni * 16 + l16;
            const int s = (d16 + (n >> 1)) & 3;
            bf_[ni] = *reinterpret_cast<const bf16x8*>(&Bs[BUF][n * 32 + s * 8]);
        }
        #pragma unroll
        for (int mi = 0; mi < 8; ++mi) {
            const int m = wr * 128 + mi * 16 + l16;
            const int s = (d16 + (m >> 1)) & 3;
            af[mi] = *reinterpret_cast<const bf16x8*>(&As[BUF][m * 32 + s * 8]);
        }
        __builtin_amdgcn_s_setprio(1);
        #pragma unroll
        for (int mi = 0; mi < 8; ++mi)
            #pragma unroll
            for (int ni = 0; ni < 4; ++ni)
                acc[mi][ni] = __builtin_amdgcn_mfma_f32_16x16x32_bf16(
                    af[mi], bf_[ni], acc[mi][ni], 0, 0, 0);
        __builtin_amdgcn_s_setprio(0);
    };

    // prologue: stage tiles 0,1,2
    STAGE(0, 0);
    STAGE(1, 1);
    STAGE(2, 2);

    // main loop: stage kt+3, wait until tile kt landed (<=12 outstanding), compute
    for (int kt = 0; kt < NT - 3; ++kt) {
        STAGE(kt + 3, (kt + 3) & 3);
        __builtin_amdgcn_sched_barrier(0);
        asm volatile("s_waitcnt vmcnt(12)" ::: "memory");
        __builtin_amdgcn_s_barrier();
        __builtin_amdgcn_sched_barrier(0);
        COMPUTE(kt & 3);
        __builtin_amdgcn_sched_barrier(0);
        __builtin_amdgcn_s_barrier();
    }
    // tail: tiles 33,34,35 (bufs 1,2,3) — drain progressively
    asm volatile("s_waitcnt vmcnt(8)" ::: "memory");
    __builtin_amdgcn_s_barrier();
    __builtin_amdgcn_sched_barrier(0);
    COMPUTE(1);
    asm volatile("s_waitcnt vmcnt(4)" ::: "memory");
    __builtin_amdgcn_s_barrier();
    __builtin_amdgcn_sched_barrier(0);
    COMPUTE(2);
    asm volatile("s_waitcnt vmcnt(0)" ::: "memory");
    __builtin_amdgcn_s_barrier();
    __builtin_amdgcn_sched_barrier(0);
    COMPUTE(3);

    // ---- epilogue: float4 stores; zero y==63 / x==63 ----
    #pragma unroll
    for (int mi = 0; mi < 8; ++mi) {
        const int m  = wr * 128 + mi * 16 + d16 * 4;   // +r contiguous in x
        const int x0 = m & 63;
        const int y  = y0 + (m >> 6);
        #pragma unroll
        for (int ni = 0; ni < 4; ++ni) {
            const int o = wc * 64 + ni * 16 + l16;
            float4 v;
            v.x = acc[mi][ni][0];
            v.y = acc[mi][ni][1];
            v.z = acc[mi][ni][2];
            v.w = acc[mi][ni][3];
            if (y == HW - 1) { v.x = v.y = v.z = v.w = 0.f; }
            if (x0 + 3 == HW - 1) v.w = 0.f;
            *reinterpret_cast<float4*>(
                out + ((long)(b * OUTC + o) * 4096 + y * 64 + x0)) = v;
        }
    }
}

// ================= fallback (round-1 kernel) if ws too small =================
__global__ __launch_bounds__(256) void conv_igemm_bf16(
    const float* __restrict__ X, const float* __restrict__ Kw, float* __restrict__ out) {
    __shared__ __hip_bfloat16 As[128][40];
    __shared__ __hip_bfloat16 Bs[128][40];
    const int tid = threadIdx.x, wave = tid >> 6, lane = tid & 63;
    const int l16 = lane & 15, d16 = lane >> 4;
    const int m_base = blockIdx.x * 128;
    const int b = m_base >> 12, y0 = (m_base & 4095) >> 6;
    const int n_base = blockIdx.y * 128;
    const int wm = (wave >> 1) * 64, wn = (wave & 1) * 64;
    f32x4 acc[4][4] = {};
    const int smm = tid & 127, ccb = tid >> 7;
    const int sx = smm & 63, syr = smm >> 6;
    for (int ij = 0; ij < 9; ++ij) {
        const int di = ij / 3 - 1, dj = ij % 3 - 1;
        const int xp = sx + dj, yp = y0 + syr + di;
        const bool ok = ((unsigned)xp < 64u) && ((unsigned)yp < 64u);
        const long xbase = (((long)b * CIN) * HW + yp) * HW + xp;
        for (int c0 = 0; c0 < CIN; c0 += 32) {
            for (int cc = ccb; cc < 32; cc += 2) {
                float v = ok ? X[xbase + (long)(c0 + cc) * 4096] : 0.f;
                As[smm][cc] = __float2bfloat16(v);
                Bs[smm][cc] = __float2bfloat16(Kw[((c0 + cc) * 9 + ij) * OUTC + n_base + smm]);
            }
            __syncthreads();
            bf16x8 afrag[4], bfrag[4];
            for (int mi = 0; mi < 4; ++mi)
                afrag[mi] = *reinterpret_cast<const bf16x8*>(&As[wm + mi * 16 + l16][d16 * 8]);
            for (int ni = 0; ni < 4; ++ni)
                bfrag[ni] = *reinterpret_cast<const bf16x8*>(&Bs[wn + ni * 16 + l16][d16 * 8]);
            for (int mi = 0; mi < 4; ++mi)
                for (int ni = 0; ni < 4; ++ni)
                    acc[mi][ni] = __builtin_amdgcn_mfma_f32_16x16x32_bf16(
                        afrag[mi], bfrag[ni], acc[mi][ni], 0, 0, 0);
            __syncthreads();
        }
    }
    for (int mi = 0; mi < 4; ++mi)
        for (int ni = 0; ni < 4; ++ni)
            for (int r = 0; r < 4; ++r) {
                const int mm = wm + mi * 16 + d16 * 4 + r;
                const int nn = wn + ni * 16 + l16;
                const int y = y0 + (mm >> 6), x = mm & 63, o = n_base + nn;
                float v = acc[mi][ni][r];
                if (y == 63 || x == 63) v = 0.f;
                out[(((long)b * OUTC + o) * HW + y) * HW + x] = v;
            }
}

extern "C" void kernel_launch(void* const* d_in, const int* in_sizes, int n_in,
                              void* d_out, int out_size, void* d_ws, size_t ws_size,
                              hipStream_t stream) {
    const float* X  = (const float*)d_in[0];
    const float* Kw = (const float*)d_in[1];
    float* out = (float*)d_out;

    if (ws_size >= WS_NEEDED) {
        char* ws = (char*)d_ws;
        __hip_bfloat16* Xt = (__hip_bfloat16*)ws;
        __hip_bfloat16* Bp = (__hip_bfloat16*)(ws + BP_OFF);
        __hip_bfloat16* zp = (__hip_bfloat16*)(ws + ZP_OFF);
        hipMemsetAsync(ws + ZP_OFF, 0, 4096, stream);
        conv_prep_x<<<dim3(2048), dim3(256), 0, stream>>>(X, Xt);
        conv_prep_b<<<dim3(1152), dim3(256), 0, stream>>>(Kw, Bp);
        conv_igemm3<<<dim3(512), dim3(512), 0, stream>>>(Xt, Bp, zp, out);
    } else {
        conv_igemm_bf16<<<dim3(1024, 2), dim3(256), 0, stream>>>(X, Kw, out);
    }
}

// Round 5
// 115.195 us; speedup vs baseline: 9.0267x; 1.1407x over previous
//
#include <hip/hip_runtime.h>
#include <hip/hip_bf16.h>

typedef __attribute__((ext_vector_type(8))) short bf16x8;
typedef __attribute__((ext_vector_type(4))) float f32x4;

#define CIN   128
#define HW    64
#define OUTC  256

#define BP_OFF     33554432ULL
#define ZP_OFF     34144256ULL
#define WS_NEEDED  34148352ULL

#define SB  __builtin_amdgcn_s_barrier()
#define SCB __builtin_amdgcn_sched_barrier(0)
#define WAITV(N) asm volatile("s_waitcnt vmcnt(" #N ")" ::: "memory")
#define WAITL    asm volatile("s_waitcnt lgkmcnt(0)" ::: "memory")
#define MFMA(a, b, c) __builtin_amdgcn_mfma_f32_16x16x32_bf16(a, b, c, 0, 0, 0)

// 16-MFMA cluster: m-frags MB..MB+3 x n-frags 0..3, setprio-wrapped (T5)
#define MFMA16(MB, A0, A1, A2, A3, B0, B1, B2, B3) do {            \
    __builtin_amdgcn_s_setprio(1);                                 \
    acc[MB+0][0] = MFMA(A0, B0, acc[MB+0][0]);                     \
    acc[MB+1][0] = MFMA(A1, B0, acc[MB+1][0]);                     \
    acc[MB+2][0] = MFMA(A2, B0, acc[MB+2][0]);                     \
    acc[MB+3][0] = MFMA(A3, B0, acc[MB+3][0]);                     \
    acc[MB+0][1] = MFMA(A0, B1, acc[MB+0][1]);                     \
    acc[MB+1][1] = MFMA(A1, B1, acc[MB+1][1]);                     \
    acc[MB+2][1] = MFMA(A2, B1, acc[MB+2][1]);                     \
    acc[MB+3][1] = MFMA(A3, B1, acc[MB+3][1]);                     \
    acc[MB+0][2] = MFMA(A0, B2, acc[MB+0][2]);                     \
    acc[MB+1][2] = MFMA(A1, B2, acc[MB+1][2]);                     \
    acc[MB+2][2] = MFMA(A2, B2, acc[MB+2][2]);                     \
    acc[MB+3][2] = MFMA(A3, B2, acc[MB+3][2]);                     \
    acc[MB+0][3] = MFMA(A0, B3, acc[MB+0][3]);                     \
    acc[MB+1][3] = MFMA(A1, B3, acc[MB+1][3]);                     \
    acc[MB+2][3] = MFMA(A2, B3, acc[MB+2][3]);                     \
    acc[MB+3][3] = MFMA(A3, B3, acc[MB+3][3]);                     \
    __builtin_amdgcn_s_setprio(0);                                 \
} while (0)

// ================= pass 1: X (b,c,y,x) f32 -> Xt (b,y,x,c) bf16 =================
__global__ __launch_bounds__(256) void conv_prep_x(const float* __restrict__ X,
                                                   __hip_bfloat16* __restrict__ Xt) {
    __shared__ __hip_bfloat16 L[64][136];
    const int b = blockIdx.x >> 6;
    const int y = blockIdx.x & 63;
    const int x = threadIdx.x & 63;
    const int c0 = (threadIdx.x >> 6) * 32;

    const float* src = X + (((long)(b * CIN + c0) * HW + y) * HW + x);
    #pragma unroll
    for (int j = 0; j < 32; j += 2) {
        float v0 = src[(long)j * (HW * HW)];
        float v1 = src[(long)(j + 1) * (HW * HW)];
        __hip_bfloat162 p;
        p.x = __float2bfloat16(v0);
        p.y = __float2bfloat16(v1);
        *reinterpret_cast<__hip_bfloat162*>(&L[x][c0 + j]) = p;
    }
    __syncthreads();

    __hip_bfloat16* dst = Xt + (long)blockIdx.x * (64 * 128);
    #pragma unroll
    for (int it = 0; it < 4; ++it) {
        int G = it * 256 + threadIdx.x;
        int xx = G >> 4, g = G & 15;
        bf16x8 v = *reinterpret_cast<const bf16x8*>(&L[xx][g * 8]);
        *reinterpret_cast<bf16x8*>(&dst[(long)G * 8]) = v;
    }
}

// ================= pass 2: Kw -> Bp (ij,n,c) bf16 =================
__global__ __launch_bounds__(256) void conv_prep_b(const float* __restrict__ Kw,
                                                   __hip_bfloat16* __restrict__ Bp) {
    int idx = blockIdx.x * 256 + threadIdx.x;  // 294912 total
    int c  = idx & 127;
    int n  = (idx >> 7) & 255;
    int ij = idx >> 15;
    Bp[idx] = __float2bfloat16(Kw[((c * 9 + ij) << 8) + n]);
}

// ================= pass 3: 8-phase implicit GEMM (m201 template) =================
// M=131072, N=256, K=1152 = 18 K-tiles of 64 (tile t: ij=t>>1, c0=(t&1)*64)
// BM=256 (4 y-rows), BN=256, 8 waves 2Mx4N, per-wave 128x64
// LDS: As/Bs [dbuf=t&1][khalf][256*32] = 128 KiB total
__global__ __launch_bounds__(512, 2) void conv_igemm4(
    const __hip_bfloat16* __restrict__ Xt,
    const __hip_bfloat16* __restrict__ Bp,
    const __hip_bfloat16* __restrict__ zp,
    float* __restrict__ out)
{
    __shared__ __hip_bfloat16 As[2][2][256 * 32];
    __shared__ __hip_bfloat16 Bs[2][2][256 * 32];

    const int tid  = threadIdx.x;
    const int wv   = tid >> 6;
    const int lane = tid & 63;
    const int l16  = lane & 15;
    const int d16  = lane >> 4;
    const int wr   = wv >> 2;        // m-offset 128*wr
    const int wc   = wv & 3;         // n-offset 64*wc

    // XCD-chunked bijective swizzle (512 % 8 == 0)
    const int bid   = blockIdx.x;
    const int mtile = (bid & 7) * 64 + (bid >> 3);
    const int b  = mtile >> 4;
    const int y0 = (mtile & 15) * 4;

    const int srow = lane >> 2;      // 0..15
    const int sg   = lane & 3;       // LDS granule slot 0..3

    f32x4 acc[8][4] = {};

    // stage one operand-half: 2 x global_load_lds (16 rows x 4 granules each)
    // swizzle (both sides): slot s of row r holds global granule (s - (r>>1)) & 3
    auto stageA = [&](int t, int kh) {
        const int ij = t >> 1;
        const int c0 = (t & 1) * 64 + kh * 32;
        const int di = ij / 3 - 1;
        const int dj = ij % 3 - 1;
        __hip_bfloat16* ldsb = &As[t & 1][kh][0];
        #pragma unroll
        for (int l = 0; l < 2; ++l) {
            const int r = wv * 32 + l * 16 + srow;
            const int G = (sg - (r >> 1)) & 3;
            const int x_ = (r & 63) + dj;
            const int y_ = y0 + (r >> 6) + di;
            const __hip_bfloat16* gp =
                ((unsigned)x_ < 64u && (unsigned)y_ < 64u)
                    ? Xt + (((long)b * 4096 + y_ * 64 + x_) * 128 + c0 + G * 8)
                    : zp;
            __builtin_amdgcn_global_load_lds(
                (const __attribute__((address_space(1))) void*)gp,
                (__attribute__((address_space(3))) void*)(ldsb + (wv * 32 + l * 16) * 32),
                16, 0, 0);
        }
    };
    auto stageB = [&](int t, int kh) {
        const int ij = t >> 1;
        const int c0 = (t & 1) * 64 + kh * 32;
        __hip_bfloat16* ldsb = &Bs[t & 1][kh][0];
        #pragma unroll
        for (int l = 0; l < 2; ++l) {
            const int r = wv * 32 + l * 16 + srow;
            const int G = (sg - (r >> 1)) & 3;
            const __hip_bfloat16* gp = Bp + (((long)ij * 256 + r) * 128 + c0 + G * 8);
            __builtin_amdgcn_global_load_lds(
                (const __attribute__((address_space(1))) void*)gp,
                (__attribute__((address_space(3))) void*)(ldsb + (wv * 32 + l * 16) * 32),
                16, 0, 0);
        }
    };
    auto rdA = [&](int d, int kh, int mi) -> bf16x8 {
        const int m = wr * 128 + mi * 16 + l16;
        const int s = (d16 + (m >> 1)) & 3;
        return *reinterpret_cast<const bf16x8*>(&As[d][kh][m * 32 + s * 8]);
    };
    auto rdB = [&](int d, int kh, int ni) -> bf16x8 {
        const int n = wc * 64 + ni * 16 + l16;
        const int s = (d16 + (n >> 1)) & 3;
        return *reinterpret_cast<const bf16x8*>(&Bs[d][kh][n * 32 + s * 8]);
    };

    // prologue: t0h0, t0h1, t1h0 (12 loads/wave)
    stageA(0, 0); stageB(0, 0);
    stageA(0, 1); stageB(0, 1);
    stageA(1, 0); stageB(1, 0);

    // phase-pair: [stA; vmcnt; SB; read A0-3+B0-3; lgkm; 16 MFMA; SB]
    //             [stB; read A4-7; SB; lgkm; 16 MFMA; SB]
    #define PAIR(D, KH, VW, STA, STB)                                        \
    do {                                                                     \
        STA;                                                                 \
        VW; SB; SCB;                                                         \
        bf16x8 A0 = rdA(D, KH, 0), A1 = rdA(D, KH, 1),                       \
               A2 = rdA(D, KH, 2), A3 = rdA(D, KH, 3);                       \
        bf16x8 B0 = rdB(D, KH, 0), B1 = rdB(D, KH, 1),                       \
               B2 = rdB(D, KH, 2), B3 = rdB(D, KH, 3);                       \
        WAITL; SCB;                                                          \
        MFMA16(0, A0, A1, A2, A3, B0, B1, B2, B3);                           \
        SB;                                                                  \
        STB;                                                                 \
        bf16x8 A4 = rdA(D, KH, 4), A5 = rdA(D, KH, 5),                       \
               A6 = rdA(D, KH, 6), A7 = rdA(D, KH, 7);                       \
        SB; WAITL; SCB;                                                      \
        MFMA16(4, A4, A5, A6, A7, B0, B1, B2, B3);                           \
        SB;                                                                  \
    } while (0)

    for (int i = 0; i < 8; ++i) {
        const int t = 2 * i;
        PAIR(0, 0, WAITV(10), stageA(t + 1, 1), stageB(t + 1, 1)); // ph1,2
        PAIR(0, 1, WAITV(10), stageA(t + 2, 0), stageB(t + 2, 0)); // ph3,4
        PAIR(1, 0, WAITV(10), stageA(t + 2, 1), stageB(t + 2, 1)); // ph5,6
        PAIR(1, 1, WAITV(10), stageA(t + 3, 0), stageB(t + 3, 0)); // ph7,8
    }
    // peeled last iter (t=16,17): only t17h1 still needs staging
    PAIR(0, 0, WAITV(10), stageA(17, 1), stageB(17, 1));
    PAIR(0, 1, WAITV(8),  (void)0, (void)0);
    PAIR(1, 0, WAITV(4),  (void)0, (void)0);
    PAIR(1, 1, WAITV(0),  (void)0, (void)0);
    #undef PAIR

    // ---- epilogue: float4 stores; zero y==63 / x==63 ----
    #pragma unroll
    for (int mi = 0; mi < 8; ++mi) {
        const int m  = wr * 128 + mi * 16 + d16 * 4;
        const int x0 = m & 63;
        const int y  = y0 + (m >> 6);
        #pragma unroll
        for (int ni = 0; ni < 4; ++ni) {
            const int o = wc * 64 + ni * 16 + l16;
            float4 v;
            v.x = acc[mi][ni][0];
            v.y = acc[mi][ni][1];
            v.z = acc[mi][ni][2];
            v.w = acc[mi][ni][3];
            if (y == HW - 1) { v.x = v.y = v.z = v.w = 0.f; }
            if (x0 + 3 == HW - 1) v.w = 0.f;
            *reinterpret_cast<float4*>(
                out + ((long)(b * OUTC + o) * 4096 + y * 64 + x0)) = v;
        }
    }
}

// ================= fallback (round-1 kernel) if ws too small =================
__global__ __launch_bounds__(256) void conv_igemm_bf16(
    const float* __restrict__ X, const float* __restrict__ Kw, float* __restrict__ out) {
    __shared__ __hip_bfloat16 As[128][40];
    __shared__ __hip_bfloat16 Bs[128][40];
    const int tid = threadIdx.x, wave = tid >> 6, lane = tid & 63;
    const int l16 = lane & 15, d16 = lane >> 4;
    const int m_base = blockIdx.x * 128;
    const int b = m_base >> 12, y0 = (m_base & 4095) >> 6;
    const int n_base = blockIdx.y * 128;
    const int wm = (wave >> 1) * 64, wn = (wave & 1) * 64;
    f32x4 acc[4][4] = {};
    const int smm = tid & 127, ccb = tid >> 7;
    const int sx = smm & 63, syr = smm >> 6;
    for (int ij = 0; ij < 9; ++ij) {
        const int di = ij / 3 - 1, dj = ij % 3 - 1;
        const int xp = sx + dj, yp = y0 + syr + di;
        const bool ok = ((unsigned)xp < 64u) && ((unsigned)yp < 64u);
        const long xbase = (((long)b * CIN) * HW + yp) * HW + xp;
        for (int c0 = 0; c0 < CIN; c0 += 32) {
            for (int cc = ccb; cc < 32; cc += 2) {
                float v = ok ? X[xbase + (long)(c0 + cc) * 4096] : 0.f;
                As[smm][cc] = __float2bfloat16(v);
                Bs[smm][cc] = __float2bfloat16(Kw[((c0 + cc) * 9 + ij) * OUTC + n_base + smm]);
            }
            __syncthreads();
            bf16x8 afrag[4], bfrag[4];
            for (int mi = 0; mi < 4; ++mi)
                afrag[mi] = *reinterpret_cast<const bf16x8*>(&As[wm + mi * 16 + l16][d16 * 8]);
            for (int ni = 0; ni < 4; ++ni)
                bfrag[ni] = *reinterpret_cast<const bf16x8*>(&Bs[wn + ni * 16 + l16][d16 * 8]);
            for (int mi = 0; mi < 4; ++mi)
                for (int ni = 0; ni < 4; ++ni)
                    acc[mi][ni] = __builtin_amdgcn_mfma_f32_16x16x32_bf16(
                        afrag[mi], bfrag[ni], acc[mi][ni], 0, 0, 0);
            __syncthreads();
        }
    }
    for (int mi = 0; mi < 4; ++mi)
        for (int ni = 0; ni < 4; ++ni)
            for (int r = 0; r < 4; ++r) {
                const int mm = wm + mi * 16 + d16 * 4 + r;
                const int nn = wn + ni * 16 + l16;
                const int y = y0 + (mm >> 6), x = mm & 63, o = n_base + nn;
                float v = acc[mi][ni][r];
                if (y == 63 || x == 63) v = 0.f;
                out[(((long)b * OUTC + o) * HW + y) * HW + x] = v;
            }
}

extern "C" void kernel_launch(void* const* d_in, const int* in_sizes, int n_in,
                              void* d_out, int out_size, void* d_ws, size_t ws_size,
                              hipStream_t stream) {
    const float* X  = (const float*)d_in[0];
    const float* Kw = (const float*)d_in[1];
    float* out = (float*)d_out;

    if (ws_size >= WS_NEEDED) {
        char* ws = (char*)d_ws;
        __hip_bfloat16* Xt = (__hip_bfloat16*)ws;
        __hip_bfloat16* Bp = (__hip_bfloat16*)(ws + BP_OFF);
        __hip_bfloat16* zp = (__hip_bfloat16*)(ws + ZP_OFF);
        hipMemsetAsync(ws + ZP_OFF, 0, 4096, stream);
        conv_prep_x<<<dim3(2048), dim3(256), 0, stream>>>(X, Xt);
        conv_prep_b<<<dim3(1152), dim3(256), 0, stream>>>(Kw, Bp);
        conv_igemm4<<<dim3(512), dim3(512), 0, stream>>>(Xt, Bp, zp, out);
    } else {
        conv_igemm_bf16<<<dim3(1024, 2), dim3(256), 0, stream>>>(X, Kw, out);
    }
}

// Round 6
// 107.396 us; speedup vs baseline: 9.6823x; 1.0726x over previous
//
#include <hip/hip_runtime.h>
#include <hip/hip_bf16.h>

typedef __attribute__((ext_vector_type(8))) short bf16x8;
typedef __attribute__((ext_vector_type(4))) float f32x4;

#define CIN   128
#define HW    64
#define OUTC  256

#define BP_OFF     33554432ULL
#define ZP_OFF     34144256ULL
#define WS_NEEDED  34148352ULL

#define SB  __builtin_amdgcn_s_barrier()
#define SCB __builtin_amdgcn_sched_barrier(0)
#define WAITV(N) asm volatile("s_waitcnt vmcnt(" #N ")" ::: "memory")
#define WAITL    asm volatile("s_waitcnt lgkmcnt(0)" ::: "memory")
#define MFMA(a, b, c) __builtin_amdgcn_mfma_f32_16x16x32_bf16(a, b, c, 0, 0, 0)

#define MFMA16(MB, A0, A1, A2, A3, B0, B1, B2, B3) do {            \
    __builtin_amdgcn_s_setprio(1);                                 \
    acc[MB+0][0] = MFMA(A0, B0, acc[MB+0][0]);                     \
    acc[MB+1][0] = MFMA(A1, B0, acc[MB+1][0]);                     \
    acc[MB+2][0] = MFMA(A2, B0, acc[MB+2][0]);                     \
    acc[MB+3][0] = MFMA(A3, B0, acc[MB+3][0]);                     \
    acc[MB+0][1] = MFMA(A0, B1, acc[MB+0][1]);                     \
    acc[MB+1][1] = MFMA(A1, B1, acc[MB+1][1]);                     \
    acc[MB+2][1] = MFMA(A2, B1, acc[MB+2][1]);                     \
    acc[MB+3][1] = MFMA(A3, B1, acc[MB+3][1]);                     \
    acc[MB+0][2] = MFMA(A0, B2, acc[MB+0][2]);                     \
    acc[MB+1][2] = MFMA(A1, B2, acc[MB+1][2]);                     \
    acc[MB+2][2] = MFMA(A2, B2, acc[MB+2][2]);                     \
    acc[MB+3][2] = MFMA(A3, B2, acc[MB+3][2]);                     \
    acc[MB+0][3] = MFMA(A0, B3, acc[MB+0][3]);                     \
    acc[MB+1][3] = MFMA(A1, B3, acc[MB+1][3]);                     \
    acc[MB+2][3] = MFMA(A2, B3, acc[MB+2][3]);                     \
    acc[MB+3][3] = MFMA(A3, B3, acc[MB+3][3]);                     \
    __builtin_amdgcn_s_setprio(0);                                 \
} while (0)

// ============ fused prep: Xt transpose + Bp transpose + zp zero ============
__global__ __launch_bounds__(256) void conv_prep(const float* __restrict__ X,
                                                 const float* __restrict__ Kw,
                                                 __hip_bfloat16* __restrict__ Xt,
                                                 __hip_bfloat16* __restrict__ Bp,
                                                 __hip_bfloat16* __restrict__ zp) {
    const int blk = blockIdx.x;
    if (blk < 2048) {
        // X (b,c,y,x) f32 -> Xt (b,y,x,c) bf16
        __shared__ __hip_bfloat16 L[64][136];
        const int b = blk >> 6;
        const int y = blk & 63;
        const int x = threadIdx.x & 63;
        const int c0 = (threadIdx.x >> 6) * 32;
        const float* src = X + (((long)(b * CIN + c0) * HW + y) * HW + x);
        #pragma unroll
        for (int j = 0; j < 32; j += 2) {
            float v0 = src[(long)j * (HW * HW)];
            float v1 = src[(long)(j + 1) * (HW * HW)];
            __hip_bfloat162 p;
            p.x = __float2bfloat16(v0);
            p.y = __float2bfloat16(v1);
            *reinterpret_cast<__hip_bfloat162*>(&L[x][c0 + j]) = p;
        }
        __syncthreads();
        __hip_bfloat16* dst = Xt + (long)blk * (64 * 128);
        #pragma unroll
        for (int it = 0; it < 4; ++it) {
            int G = it * 256 + threadIdx.x;
            int xx = G >> 4, g = G & 15;
            bf16x8 v = *reinterpret_cast<const bf16x8*>(&L[xx][g * 8]);
            *reinterpret_cast<bf16x8*>(&dst[(long)G * 8]) = v;
        }
    } else if (blk < 2112) {
        // Kw (k=c*9+ij, n) f32 -> Bp (ij,n,c) bf16
        for (int idx = (blk - 2048) * 256 + threadIdx.x; idx < 294912; idx += 64 * 256) {
            int c  = idx & 127;
            int n  = (idx >> 7) & 255;
            int ij = idx >> 15;
            Bp[idx] = __float2bfloat16(Kw[((c * 9 + ij) << 8) + n]);
        }
    } else {
        // zero page (4 KB)
        *reinterpret_cast<float4*>((char*)zp + threadIdx.x * 16) = float4{0.f, 0.f, 0.f, 0.f};
    }
}

// ================= 8-phase implicit GEMM, fully unrolled K-loop =================
// M=131072, N=256, K=1152 = 18 K-tiles of 64 (tile t: ij=t>>1, c0=(t&1)*64)
// BM=256 (4 y-rows), BN=256, 8 waves 2Mx4N, per-wave 128x64
// LDS: As/Bs [dbuf=t&1][khalf][256*32] = 128 KiB total
__global__ __launch_bounds__(512, 2) void conv_igemm5(
    const __hip_bfloat16* __restrict__ Xt,
    const __hip_bfloat16* __restrict__ Bp,
    const __hip_bfloat16* __restrict__ zp,
    float* __restrict__ out)
{
    __shared__ __hip_bfloat16 As[2][2][256 * 32];
    __shared__ __hip_bfloat16 Bs[2][2][256 * 32];

    const int tid  = threadIdx.x;
    const int wv   = tid >> 6;
    const int lane = tid & 63;
    const int l16  = lane & 15;
    const int d16  = lane >> 4;
    const int wr   = wv >> 2;
    const int wc   = wv & 3;

    // XCD-chunked bijective swizzle (512 % 8 == 0)
    const int bid   = blockIdx.x;
    const int mtile = (bid & 7) * 64 + (bid >> 3);
    const int b  = mtile >> 4;
    const int y0 = (mtile & 15) * 4;

    const int srow = lane >> 2;
    const int sg   = lane & 3;

    f32x4 acc[8][4] = {};

    // ---- hoisted per-lane staging bases (swizzle: slot s of row r holds G=(s-(r>>1))&3) ----
    const int r0  = wv * 32 + srow;
    const int r1  = r0 + 16;
    const int G0  = (sg - (r0 >> 1)) & 3;
    const int G1  = (sg - (r1 >> 1)) & 3;
    const int xr0 = r0 & 63, xr1 = r1 & 63;
    const int yy0 = y0 + (r0 >> 6), yy1 = y0 + (r1 >> 6);
    const __hip_bfloat16* pA0 = Xt + (((long)b * 4096 + yy0 * 64 + xr0) * 128 + G0 * 8);
    const __hip_bfloat16* pA1 = Xt + (((long)b * 4096 + yy1 * 64 + xr1) * 128 + G1 * 8);
    const __hip_bfloat16* pB0 = Bp + ((long)r0 * 128 + G0 * 8);
    const __hip_bfloat16* pB1 = Bp + ((long)r1 * 128 + G1 * 8);
    const int ldsOff0 = (wv * 32) * 32;        // bf16 elements
    const int ldsOff1 = (wv * 32 + 16) * 32;

    auto stageA = [&](int t, int kh) {
        const int ij = t >> 1;                    // literal after unroll
        const int c0 = (t & 1) * 64 + kh * 32;
        const int di = ij / 3 - 1;
        const int dj = ij % 3 - 1;
        const long off = (long)(di * 64 + dj) * 128 + c0;
        const bool ok0 = ((unsigned)(xr0 + dj) < 64u) && ((unsigned)(yy0 + di) < 64u);
        const bool ok1 = ((unsigned)(xr1 + dj) < 64u) && ((unsigned)(yy1 + di) < 64u);
        const __hip_bfloat16* g0 = ok0 ? pA0 + off : zp + c0;
        const __hip_bfloat16* g1 = ok1 ? pA1 + off : zp + c0;
        __builtin_amdgcn_global_load_lds(
            (const __attribute__((address_space(1))) void*)g0,
            (__attribute__((address_space(3))) void*)(&As[t & 1][kh][0] + ldsOff0), 16, 0, 0);
        __builtin_amdgcn_global_load_lds(
            (const __attribute__((address_space(1))) void*)g1,
            (__attribute__((address_space(3))) void*)(&As[t & 1][kh][0] + ldsOff1), 16, 0, 0);
    };
    auto stageB = [&](int t, int kh) {
        const long off = (long)(t >> 1) * 32768 + (t & 1) * 64 + kh * 32;
        __builtin_amdgcn_global_load_lds(
            (const __attribute__((address_space(1))) void*)(pB0 + off),
            (__attribute__((address_space(3))) void*)(&Bs[t & 1][kh][0] + ldsOff0), 16, 0, 0);
        __builtin_amdgcn_global_load_lds(
            (const __attribute__((address_space(1))) void*)(pB1 + off),
            (__attribute__((address_space(3))) void*)(&Bs[t & 1][kh][0] + ldsOff1), 16, 0, 0);
    };
    auto rdA = [&](int d, int kh, int mi) -> bf16x8 {
        const int m = wr * 128 + mi * 16 + l16;
        const int s = (d16 + (m >> 1)) & 3;
        return *reinterpret_cast<const bf16x8*>(&As[d][kh][m * 32 + s * 8]);
    };
    auto rdB = [&](int d, int kh, int ni) -> bf16x8 {
        const int n = wc * 64 + ni * 16 + l16;
        const int s = (d16 + (n >> 1)) & 3;
        return *reinterpret_cast<const bf16x8*>(&Bs[d][kh][n * 32 + s * 8]);
    };

    // prologue: t0h0, t0h1, t1h0 (12 loads/wave)
    stageA(0, 0); stageB(0, 0);
    stageA(0, 1); stageB(0, 1);
    stageA(1, 0); stageB(1, 0);

    #define PAIR(D, KH, VW, STA, STB)                                        \
    do {                                                                     \
        STA;                                                                 \
        VW; SB; SCB;                                                         \
        bf16x8 A0 = rdA(D, KH, 0), A1 = rdA(D, KH, 1),                       \
               A2 = rdA(D, KH, 2), A3 = rdA(D, KH, 3);                       \
        bf16x8 B0 = rdB(D, KH, 0), B1 = rdB(D, KH, 1),                       \
               B2 = rdB(D, KH, 2), B3 = rdB(D, KH, 3);                       \
        WAITL; SCB;                                                          \
        MFMA16(0, A0, A1, A2, A3, B0, B1, B2, B3);                           \
        SB;                                                                  \
        STB;                                                                 \
        bf16x8 A4 = rdA(D, KH, 4), A5 = rdA(D, KH, 5),                       \
               A6 = rdA(D, KH, 6), A7 = rdA(D, KH, 7);                       \
        SB; WAITL; SCB;                                                      \
        MFMA16(4, A4, A5, A6, A7, B0, B1, B2, B3);                           \
        SB;                                                                  \
    } while (0)

    #pragma unroll
    for (int i = 0; i < 8; ++i) {
        const int t = 2 * i;
        PAIR(0, 0, WAITV(10), stageA(t + 1, 1), stageB(t + 1, 1));
        PAIR(0, 1, WAITV(10), stageA(t + 2, 0), stageB(t + 2, 0));
        PAIR(1, 0, WAITV(10), stageA(t + 2, 1), stageB(t + 2, 1));
        PAIR(1, 1, WAITV(10), stageA(t + 3, 0), stageB(t + 3, 0));
    }
    // peeled last iter (t=16,17)
    PAIR(0, 0, WAITV(10), stageA(17, 1), stageB(17, 1));
    PAIR(0, 1, WAITV(8),  (void)0, (void)0);
    PAIR(1, 0, WAITV(4),  (void)0, (void)0);
    PAIR(1, 1, WAITV(0),  (void)0, (void)0);
    #undef PAIR

    // ---- epilogue: float4 stores (each instr fills whole 64B lines); zero y==63 / x==63 ----
    #pragma unroll
    for (int mi = 0; mi < 8; ++mi) {
        const int m  = wr * 128 + mi * 16 + d16 * 4;
        const int x0 = m & 63;
        const int y  = y0 + (m >> 6);
        #pragma unroll
        for (int ni = 0; ni < 4; ++ni) {
            const int o = wc * 64 + ni * 16 + l16;
            float4 v;
            v.x = acc[mi][ni][0];
            v.y = acc[mi][ni][1];
            v.z = acc[mi][ni][2];
            v.w = acc[mi][ni][3];
            if (y == HW - 1) { v.x = v.y = v.z = v.w = 0.f; }
            if (x0 + 3 == HW - 1) v.w = 0.f;
            *reinterpret_cast<float4*>(
                out + ((long)(b * OUTC + o) * 4096 + y * 64 + x0)) = v;
        }
    }
}

// ================= fallback (round-1 kernel) if ws too small =================
__global__ __launch_bounds__(256) void conv_igemm_bf16(
    const float* __restrict__ X, const float* __restrict__ Kw, float* __restrict__ out) {
    __shared__ __hip_bfloat16 As[128][40];
    __shared__ __hip_bfloat16 Bs[128][40];
    const int tid = threadIdx.x, wave = tid >> 6, lane = tid & 63;
    const int l16 = lane & 15, d16 = lane >> 4;
    const int m_base = blockIdx.x * 128;
    const int b = m_base >> 12, y0 = (m_base & 4095) >> 6;
    const int n_base = blockIdx.y * 128;
    const int wm = (wave >> 1) * 64, wn = (wave & 1) * 64;
    f32x4 acc[4][4] = {};
    const int smm = tid & 127, ccb = tid >> 7;
    const int sx = smm & 63, syr = smm >> 6;
    for (int ij = 0; ij < 9; ++ij) {
        const int di = ij / 3 - 1, dj = ij % 3 - 1;
        const int xp = sx + dj, yp = y0 + syr + di;
        const bool ok = ((unsigned)xp < 64u) && ((unsigned)yp < 64u);
        const long xbase = (((long)b * CIN) * HW + yp) * HW + xp;
        for (int c0 = 0; c0 < CIN; c0 += 32) {
            for (int cc = ccb; cc < 32; cc += 2) {
                float v = ok ? X[xbase + (long)(c0 + cc) * 4096] : 0.f;
                As[smm][cc] = __float2bfloat16(v);
                Bs[smm][cc] = __float2bfloat16(Kw[((c0 + cc) * 9 + ij) * OUTC + n_base + smm]);
            }
            __syncthreads();
            bf16x8 afrag[4], bfrag[4];
            for (int mi = 0; mi < 4; ++mi)
                afrag[mi] = *reinterpret_cast<const bf16x8*>(&As[wm + mi * 16 + l16][d16 * 8]);
            for (int ni = 0; ni < 4; ++ni)
                bfrag[ni] = *reinterpret_cast<const bf16x8*>(&Bs[wn + ni * 16 + l16][d16 * 8]);
            for (int mi = 0; mi < 4; ++mi)
                for (int ni = 0; ni < 4; ++ni)
                    acc[mi][ni] = __builtin_amdgcn_mfma_f32_16x16x32_bf16(
                        afrag[mi], bfrag[ni], acc[mi][ni], 0, 0, 0);
            __syncthreads();
        }
    }
    for (int mi = 0; mi < 4; ++mi)
        for (int ni = 0; ni < 4; ++ni)
            for (int r = 0; r < 4; ++r) {
                const int mm = wm + mi * 16 + d16 * 4 + r;
                const int nn = wn + ni * 16 + l16;
                const int y = y0 + (mm >> 6), x = mm & 63, o = n_base + nn;
                float v = acc[mi][ni][r];
                if (y == 63 || x == 63) v = 0.f;
                out[(((long)b * OUTC + o) * HW + y) * HW + x] = v;
            }
}

extern "C" void kernel_launch(void* const* d_in, const int* in_sizes, int n_in,
                              void* d_out, int out_size, void* d_ws, size_t ws_size,
                              hipStream_t stream) {
    const float* X  = (const float*)d_in[0];
    const float* Kw = (const float*)d_in[1];
    float* out = (float*)d_out;

    if (ws_size >= WS_NEEDED) {
        char* ws = (char*)d_ws;
        __hip_bfloat16* Xt = (__hip_bfloat16*)ws;
        __hip_bfloat16* Bp = (__hip_bfloat16*)(ws + BP_OFF);
        __hip_bfloat16* zp = (__hip_bfloat16*)(ws + ZP_OFF);
        conv_prep<<<dim3(2113), dim3(256), 0, stream>>>(X, Kw, Xt, Bp, zp);
        conv_igemm5<<<dim3(512), dim3(512), 0, stream>>>(Xt, Bp, zp, out);
    } else {
        conv_igemm_bf16<<<dim3(1024, 2), dim3(256), 0, stream>>>(X, Kw, out);
    }
}